// Round 15
// baseline (11318.060 us; speedup 1.0000x reference)
//
#include <hip/hip_runtime.h>
#include <stdint.h>

typedef unsigned short u16;
typedef unsigned int u32;
typedef __attribute__((ext_vector_type(8))) short short8;
typedef __attribute__((ext_vector_type(4))) float f32x4;

#define T_SEQ 512
#define NB 32
#define EMBD 1024
#define HID 512
#define G4 2048
#define NROWS (T_SEQ * NB)  // 16384
#define XPW 4096
#define SENTW 0xFFFFFFFFu

static __device__ __forceinline__ u16 f2bf(float x) {
  unsigned u = __float_as_uint(x);
  u += 0x7fffu + ((u >> 16) & 1u);
  return (u16)(u >> 16);
}
static __device__ __forceinline__ float bf2f(u16 b) {
  return __uint_as_float(((unsigned)b) << 16);
}
static __device__ __forceinline__ f32x4 mfma16(short8 a, short8 b, f32x4 c) {
  return __builtin_amdgcn_mfma_f32_16x16x32_bf16(a, b, c, 0, 0, 0);
}
static __device__ __forceinline__ float fast_tanh(float x) {
  float e = __expf(2.f * x);
  return 1.f - 2.f / (e + 1.f);
}
static __device__ __forceinline__ float sigm(float x) {
  return 1.f / (1.f + __expf(-x));
}
static __device__ __forceinline__ void barrier_lds() {
  asm volatile("s_waitcnt lgkmcnt(0)" ::: "memory");
  __builtin_amdgcn_s_barrier();
  asm volatile("" ::: "memory");
}

// ---------------- weight prep: bf16 convert, Whh split hi/lo, bias merge ----
__global__ void k_prep(const float* __restrict__ Wih, const float* __restrict__ Whh,
                       const float* __restrict__ bih, const float* __restrict__ bhh,
                       u16* __restrict__ wih_b, u16* __restrict__ whh_hi,
                       u16* __restrict__ whh_lo, float* __restrict__ bcat) {
  size_t stride = (size_t)gridDim.x * blockDim.x;
  size_t i0 = (size_t)blockIdx.x * blockDim.x + threadIdx.x;
  const size_t n_ih = (size_t)2 * 2 * G4 * EMBD;  // [l][d][4H][E]
  for (size_t i = i0; i < n_ih; i += stride) wih_b[i] = f2bf(Wih[i]);
  const size_t n_hh = (size_t)2 * 2 * G4 * HID;   // [l][d][4H][H]
  for (size_t i = i0; i < n_hh; i += stride) {
    float w = Whh[i];
    u16 hi = f2bf(w);
    whh_hi[i] = hi;
    whh_lo[i] = f2bf(w - bf2f(hi));
  }
  for (size_t i = i0; i < 2 * 4096; i += stride) {
    size_t l = i >> 12, col = i & 4095;  // col = d*2048+g*512+u
    bcat[i] = bih[l * 4096 + col] + bhh[l * 4096 + col];
  }
}

// ---------------- embedding gather -> bf16 X [T*B, 1024] --------------------
__global__ void k_gather(const int* __restrict__ inp, const float* __restrict__ emb,
                         u16* __restrict__ X) {
  int row = blockIdx.x;  // t*32 + b
  int t = row >> 5, b = row & 31;
  int tok = inp[b * T_SEQ + t];
  const float* src = emb + (size_t)tok * EMBD + threadIdx.x * 4;
  float4 v = *reinterpret_cast<const float4*>(src);
  ushort4 o;
  o.x = f2bf(v.x); o.y = f2bf(v.y); o.z = f2bf(v.z); o.w = f2bf(v.w);
  *reinterpret_cast<ushort4*>(X + (size_t)row * EMBD + threadIdx.x * 4) = o;
}

// ---------------- xp GEMM: C[M,4096] = A[M,1024] @ B[4096,1024]^T + bias ----
// PACKED=0: A is bf16. PACKED=1: A is packed u32 (hi<<16|lo), use hi bf16.
#define GBM 128
#define GBN 128
#define GBK 64
template <int PACKED>
__global__ __launch_bounds__(256) void k_gemm(const void* __restrict__ Av,
                                              const u16* __restrict__ B,
                                              const float* __restrict__ bias,
                                              u16* __restrict__ C) {
  __shared__ u16 As[GBM][GBK];
  __shared__ u16 Bs[GBN][GBK];
  const int Kdim = 1024, Ndim = 4096;
  int bm = blockIdx.x, bn = blockIdx.y;
  int tid = threadIdx.x;
  int lane = tid & 63, wave = tid >> 6;
  int wm = wave >> 1, wn = wave & 1;
  int l15 = lane & 15, klo = (lane >> 4) * 8;
  f32x4 acc[4][4] = {};
  for (int k0 = 0; k0 < Kdim; k0 += GBK) {
#pragma unroll
    for (int s = 0; s < 4; s++) {
      int seg = tid + s * 256;
      int r = seg >> 3, cs = (seg & 7) * 8;
      if (PACKED) {
        const u32* srcp = (const u32*)Av + (size_t)(bm * GBM + r) * Kdim + k0 + cs;
        uint4 a = *reinterpret_cast<const uint4*>(srcp);
        uint4 b = *reinterpret_cast<const uint4*>(srcp + 4);
        uint4 o;
        o.x = __builtin_amdgcn_perm(a.y, a.x, 0x07060302u);
        o.y = __builtin_amdgcn_perm(a.w, a.z, 0x07060302u);
        o.z = __builtin_amdgcn_perm(b.y, b.x, 0x07060302u);
        o.w = __builtin_amdgcn_perm(b.w, b.z, 0x07060302u);
        *reinterpret_cast<uint4*>(&As[r][cs]) = o;
      } else {
        *reinterpret_cast<short8*>(&As[r][cs]) = *reinterpret_cast<const short8*>(
            (const u16*)Av + (size_t)(bm * GBM + r) * Kdim + k0 + cs);
      }
      *reinterpret_cast<short8*>(&Bs[r][cs]) =
          *reinterpret_cast<const short8*>(B + (size_t)(bn * GBN + r) * Kdim + k0 + cs);
    }
    __syncthreads();
#pragma unroll
    for (int kk = 0; kk < GBK; kk += 32) {
      short8 af[4], bfb[4];
#pragma unroll
      for (int i = 0; i < 4; i++)
        af[i] = *reinterpret_cast<const short8*>(&As[wm * 64 + i * 16 + l15][kk + klo]);
#pragma unroll
      for (int j = 0; j < 4; j++)
        bfb[j] = *reinterpret_cast<const short8*>(&Bs[wn * 64 + j * 16 + l15][kk + klo]);
#pragma unroll
      for (int i = 0; i < 4; i++)
#pragma unroll
        for (int j = 0; j < 4; j++)
          acc[i][j] = mfma16(af[i], bfb[j], acc[i][j]);
    }
    __syncthreads();
  }
  int lg4 = (lane >> 4) * 4;
#pragma unroll
  for (int i = 0; i < 4; i++) {
#pragma unroll
    for (int j = 0; j < 4; j++) {
      int n = bn * GBN + wn * 64 + j * 16 + l15;
      float bv = bias[n];
#pragma unroll
      for (int r = 0; r < 4; r++) {
        int m = bm * GBM + wm * 64 + i * 16 + lg4 + r;
        C[(size_t)m * Ndim + n] = f2bf(acc[i][j][r] + bv);
      }
    }
  }
}

// ---------------- recurrent layer: XCD-local sync, deferred LLC mirror ------
// grid=256; blk%8==0 -> dir0 worker, ==1 -> dir1 worker, slice=blk>>3: all 32
// WGs of a direction land on one XCD (round-robin dispatch; speed heuristic
// only). h published as PLAIN store (shared local L2, ~200cy visible). Poll
// with sc0 (L1-bypass, local-L2 hit). LLC mirror (sc0 sc1) DEFERRED: issued
// after the NEXT step's poll detects (drains under MFMA, never inside a
// poll's vmcnt) + final post-loop flush. Mirror serves only the sticky
// use_llc fallback (512 failed polls -> poll LLC) => correct under ANY
// placement, fast under the %8 heuristic (r9's FETCH collapse proved it).
__global__ __launch_bounds__(256, 1) void k_lstm15(const u16* __restrict__ xp,
                                                   const u16* __restrict__ whh_hi,
                                                   const u16* __restrict__ whh_lo,
                                                   u32* __restrict__ ypk) {
  int blk = blockIdx.x;
  int role = blk & 7;
  if (role > 1) return;  // 192 idle WGs exit immediately
  int dir = role, slice = blk >> 3;
  int tid = threadIdx.x, wave = tid >> 6, lane = tid & 63;
  int u0 = slice * 16;
  int l15 = lane & 15, lg = lane >> 4;
  int klo = lg * 8;

  f32x4 whf[4][4], wlf[4][4];
#pragma unroll
  for (int ct = 0; ct < 4; ct++) {
    size_t wr = ((size_t)dir * G4 + ct * HID + u0 + l15) * HID + wave * 128 + klo;
#pragma unroll
    for (int kt = 0; kt < 4; kt++) {
      whf[ct][kt] = *reinterpret_cast<const f32x4*>(whh_hi + wr + kt * 32);
      wlf[ct][kt] = *reinterpret_cast<const f32x4*>(whh_lo + wr + kt * 32);
    }
  }
#pragma unroll
  for (int ct = 0; ct < 4; ct++)
#pragma unroll
    for (int kt = 0; kt < 4; kt++) {
      asm volatile("" : "+v"(whf[ct][kt]));
      asm volatile("" : "+v"(wlf[ct][kt]));
    }

  __shared__ float pgx[4][NB][16][5];  // [gate][b][uu][wave+pad]
  float cst[2] = {0.f, 0.f};
  int bj[2], uj[2];
#pragma unroll
  for (int j = 0; j < 2; j++) {
    int p = tid + 256 * j;
    uj[j] = p & 15;
    bj[j] = p >> 4;
  }
  int use_llc = 0;       // sticky fallback if co-location heuristic fails
  int have_m = 0;        // deferred-mirror valid?
  u32 mv0 = 0, mv1 = 0;  // deferred mirror values
  u32 *ma0 = ypk, *ma1 = ypk;  // deferred mirror addresses

  for (int s = 0; s < T_SEQ; s++) {
    int trow = dir ? (T_SEQ - 1 - s) : s;
    short8 ah[2][4], al[2][4];
    if (s > 0) {
      int prow = dir ? (T_SEQ - s) : (s - 1);
      const u32* yb = ypk + ((size_t)prow * NB + l15) * 1024 + dir * HID + wave * 128 + klo;
      uint4 hb[2][4][2];
      int tries = 0;
      // ---- data-poll: local-L2 (sc0) fast path, LLC (sc0sc1) fallback ----
      while (true) {
        if (!use_llc) {
#pragma unroll
          for (int mt = 0; mt < 2; mt++) {
            const u32* pb = yb + (size_t)mt * 16 * 1024;
#pragma unroll
            for (int kt = 0; kt < 4; kt++) {
              asm volatile("global_load_dwordx4 %0, %1, off offset:%2 sc0"
                           : "=&v"(hb[mt][kt][0]) : "v"(pb), "i"(kt * 128));
              asm volatile("global_load_dwordx4 %0, %1, off offset:%2 sc0"
                           : "=&v"(hb[mt][kt][1]) : "v"(pb), "i"(kt * 128 + 16));
            }
          }
        } else {
#pragma unroll
          for (int mt = 0; mt < 2; mt++) {
            const u32* pb = yb + (size_t)mt * 16 * 1024;
#pragma unroll
            for (int kt = 0; kt < 4; kt++) {
              asm volatile("global_load_dwordx4 %0, %1, off offset:%2 sc0 sc1"
                           : "=&v"(hb[mt][kt][0]) : "v"(pb), "i"(kt * 128));
              asm volatile("global_load_dwordx4 %0, %1, off offset:%2 sc0 sc1"
                           : "=&v"(hb[mt][kt][1]) : "v"(pb), "i"(kt * 128 + 16));
            }
          }
        }
        asm volatile("s_waitcnt vmcnt(0)" ::: "memory");
        __builtin_amdgcn_sched_barrier(0);
        u32 mx = 0;  // SENTW == u32 max: any sentinel word makes mx == SENTW
#pragma unroll
        for (int mt = 0; mt < 2; mt++)
#pragma unroll
          for (int kt = 0; kt < 4; kt++)
#pragma unroll
            for (int h2 = 0; h2 < 2; h2++) {
              uint4 v = hb[mt][kt][h2];
              mx = max(mx, max(max(v.x, v.y), max(v.z, v.w)));
            }
        if (__all(mx != SENTW)) break;
        if (++tries == 512) use_llc = 1;
      }
      // flush previous step's LLC mirrors now (drains under MFMA phase)
      if (have_m) {
        asm volatile("global_store_dword %0, %1, off sc0 sc1" :: "v"(ma0), "v"(mv0) : "memory");
        asm volatile("global_store_dword %0, %1, off sc0 sc1" :: "v"(ma1), "v"(mv1) : "memory");
      }
      // unpack hi|lo via byte-perms
#pragma unroll
      for (int mt = 0; mt < 2; mt++)
#pragma unroll
        for (int kt = 0; kt < 4; kt++) {
          uint4 a = hb[mt][kt][0], b = hb[mt][kt][1];
          u32 v8[8] = {a.x, a.y, a.z, a.w, b.x, b.y, b.z, b.w};
          union { short8 s8; u32 u[4]; } uh, ul;
#pragma unroll
          for (int i = 0; i < 4; i++) {
            uh.u[i] = __builtin_amdgcn_perm(v8[2 * i + 1], v8[2 * i], 0x07060302u);
            ul.u[i] = __builtin_amdgcn_perm(v8[2 * i + 1], v8[2 * i], 0x05040100u);
          }
          ah[mt][kt] = uh.s8;
          al[mt][kt] = ul.s8;
        }
    }
    // ---- issue xq loads now (no wait): latency hides under MFMA phase ----
    u32 xqr[2][4];
#pragma unroll
    for (int j = 0; j < 2; j++) {
      const u16* xb = xp + (size_t)(trow * NB + bj[j]) * XPW + dir * 2048 + u0 + uj[j];
#pragma unroll
      for (int g = 0; g < 4; g++)
        asm volatile("global_load_ushort %0, %1, off offset:%2"
                     : "=&v"(xqr[j][g]) : "v"(xb), "i"(g * HID * 2));
    }
    if (s > 0) {
      f32x4 accM[2][4], accC[2][4];
#pragma unroll
      for (int mt = 0; mt < 2; mt++)
#pragma unroll
        for (int ct = 0; ct < 4; ct++) {
          accM[mt][ct] = (f32x4){0.f, 0.f, 0.f, 0.f};
          accC[mt][ct] = (f32x4){0.f, 0.f, 0.f, 0.f};
        }
#pragma unroll
      for (int kt = 0; kt < 4; kt++)
#pragma unroll
        for (int mt = 0; mt < 2; mt++)
#pragma unroll
          for (int ct = 0; ct < 4; ct++) {
            short8 wh = __builtin_bit_cast(short8, whf[ct][kt]);
            short8 wl = __builtin_bit_cast(short8, wlf[ct][kt]);
            accM[mt][ct] = mfma16(ah[mt][kt], wh, accM[mt][ct]);
            accC[mt][ct] = mfma16(al[mt][kt], wh, accC[mt][ct]);
            accC[mt][ct] = mfma16(ah[mt][kt], wl, accC[mt][ct]);
          }
#pragma unroll
      for (int mt = 0; mt < 2; mt++)
#pragma unroll
        for (int ct = 0; ct < 4; ct++) {
          f32x4 v4 = accM[mt][ct] + accC[mt][ct];
#pragma unroll
          for (int r = 0; r < 4; r++)
            pgx[ct][mt * 16 + lg * 4 + r][l15][wave] = v4[r];
        }
    }
    barrier_lds();  // pgx writes visible
    asm volatile("s_waitcnt vmcnt(0)" ::: "memory");  // xq (+mirrors) drained
    __builtin_amdgcn_sched_barrier(0);
#pragma unroll
    for (int j = 0; j < 2; j++) {
      int b = bj[j], uu = uj[j];
      float gs[4];
#pragma unroll
      for (int g = 0; g < 4; g++) {
        float v = bf2f((u16)xqr[j][g]);
        if (s > 0)
          v += (pgx[g][b][uu][0] + pgx[g][b][uu][1]) +
               (pgx[g][b][uu][2] + pgx[g][b][uu][3]);
        gs[g] = v;
      }
      float iv = sigm(gs[0]);
      float fv = sigm(gs[1]);
      float gv = fast_tanh(gs[2]);
      float ov = sigm(gs[3]);
      float c = fv * cst[j] + iv * gv;
      cst[j] = c;
      float h = ov * fast_tanh(c);
      u16 hh = f2bf(h);
      u16 hl = f2bf(h - bf2f(hh));
      size_t yo = ((size_t)trow * NB + b) * 1024 + dir * HID + u0 + uu;
      u32 pkv = ((u32)hh << 16) | hl;
      u32* addr = ypk + yo;
      // plain store -> shared local L2 (fast path for co-located consumers)
      asm volatile("global_store_dword %0, %1, off" :: "v"(addr), "v"(pkv) : "memory");
      if (j == 0) { mv0 = pkv; ma0 = addr; } else { mv1 = pkv; ma1 = addr; }
    }
    have_m = 1;
    barrier_lds();  // protect pgx reads before next step's writes
  }
  // final-step mirrors: fallback consumers (if any) need step T-1 in LLC
  asm volatile("global_store_dword %0, %1, off sc0 sc1" :: "v"(ma0), "v"(mv0) : "memory");
  asm volatile("global_store_dword %0, %1, off sc0 sc1" :: "v"(ma1), "v"(mv1) : "memory");
}

// ---------------- final pooled dot ------------------------------------------
__global__ void k_out(const u32* __restrict__ ypk, const float* __restrict__ wout,
                      const float* __restrict__ bout, float* __restrict__ out) {
  int b = blockIdx.x;
  __shared__ float red[256];
  float s = 0.f;
  for (int c = threadIdx.x; c < 1024; c += 256) {
    size_t row = (c < 512) ? ((size_t)(T_SEQ - 1) * NB + b) : (size_t)b;
    u32 pk = ypk[row * 1024 + c];
    float h = bf2f((u16)(pk >> 16)) + bf2f((u16)(pk & 0xFFFFu));
    s += h * wout[c];
  }
  red[threadIdx.x] = s;
  __syncthreads();
  for (int st = 128; st > 0; st >>= 1) {
    if (threadIdx.x < st) red[threadIdx.x] += red[threadIdx.x + st];
    __syncthreads();
  }
  if (threadIdx.x == 0) out[b] = red[0] + bout[0];
}

extern "C" void kernel_launch(void* const* d_in, const int* in_sizes, int n_in,
                              void* d_out, int out_size, void* d_ws, size_t ws_size,
                              hipStream_t stream) {
  const int*   inp  = (const int*)d_in[0];
  const float* emb  = (const float*)d_in[1];
  const float* Wih  = (const float*)d_in[2];
  const float* Whh  = (const float*)d_in[3];
  const float* bih  = (const float*)d_in[4];
  const float* bhh  = (const float*)d_in[5];
  const float* Wout = (const float*)d_in[6];
  const float* bout = (const float*)d_in[7];
  float* out = (float*)d_out;
  char* ws = (char*)d_ws;

  const size_t SZ_XP  = (size_t)NROWS * XPW * 2;   // 134 MB
  const size_t SZ_YPK = (size_t)NROWS * 1024 * 4;  // 67 MB
  const size_t SZ_WIH = (size_t)2 * 4096 * 1024 * 2;
  const size_t SZ_WHH = (size_t)2 * 2 * G4 * HID * 2;
  size_t off = 0;
  auto alloc = [&](size_t n) { size_t o = off; off += (n + 255) & ~(size_t)255; return o; };
  size_t o_xp   = alloc(SZ_XP);
  size_t o_ypkA = alloc(SZ_YPK);
  size_t o_ypkB = alloc(SZ_YPK);  // first 34 MB doubles as X1 (dead pre-memset)
  size_t o_wih  = alloc(SZ_WIH);
  size_t o_whhh = alloc(SZ_WHH);
  size_t o_whhl = alloc(SZ_WHH);
  size_t o_bc   = alloc(2 * 4096 * sizeof(float));
  if (ws_size < off) return;

  u16* xp   = (u16*)(ws + o_xp);
  u32* ypkA = (u32*)(ws + o_ypkA);
  u32* ypkB = (u32*)(ws + o_ypkB);
  u16* x1   = (u16*)(ws + o_ypkB);  // alias: dead before ypkB memset
  u16* wihb = (u16*)(ws + o_wih);
  u16* whhh = (u16*)(ws + o_whhh);
  u16* whhl = (u16*)(ws + o_whhl);
  float* bc = (float*)(ws + o_bc);

  (void)hipMemsetAsync(ypkA, 0xFF, SZ_YPK, stream);  // sentinel layer-1 h
  k_prep<<<4096, 256, 0, stream>>>(Wih, Whh, bih, bhh, wihb, whhh, whhl, bc);
  k_gather<<<NROWS, 256, 0, stream>>>(inp, emb, x1);
  k_gemm<0><<<dim3(NROWS / GBM, XPW / GBN), 256, 0, stream>>>(x1, wihb, bc, xp);
  k_lstm15<<<256, 256, 0, stream>>>(xp, whhh, whhl, ypkA);
  k_gemm<1><<<dim3(NROWS / GBM, XPW / GBN), 256, 0, stream>>>(
      ypkA, wihb + (size_t)4096 * 1024, bc + 4096, xp);
  (void)hipMemsetAsync(ypkB, 0xFF, SZ_YPK, stream);  // sentinel layer-2 h
  k_lstm15<<<256, 256, 0, stream>>>(xp, whhh + (size_t)2 * G4 * HID,
                                    whhl + (size_t)2 * G4 * HID, ypkB);
  k_out<<<NB, 256, 0, stream>>>(ypkB, Wout, bout, out);
}

// Round 16
// 9372.523 us; speedup vs baseline: 1.2076x; 1.2076x over previous
//
#include <hip/hip_runtime.h>
#include <stdint.h>

typedef unsigned short u16;
typedef unsigned int u32;
typedef __attribute__((ext_vector_type(8))) short short8;
typedef __attribute__((ext_vector_type(4))) float f32x4;

#define T_SEQ 512
#define NB 32
#define EMBD 1024
#define HID 512
#define G4 2048
#define NROWS (T_SEQ * NB)  // 16384
#define XPW 4096
#define SENTW 0xFFFFFFFFu
#define NGRID 2048
#define TICK_OVF 1984

static __device__ __forceinline__ u16 f2bf(float x) {
  unsigned u = __float_as_uint(x);
  u += 0x7fffu + ((u >> 16) & 1u);
  return (u16)(u >> 16);
}
static __device__ __forceinline__ float bf2f(u16 b) {
  return __uint_as_float(((unsigned)b) << 16);
}
static __device__ __forceinline__ f32x4 mfma16(short8 a, short8 b, f32x4 c) {
  return __builtin_amdgcn_mfma_f32_16x16x32_bf16(a, b, c, 0, 0, 0);
}
static __device__ __forceinline__ float fast_tanh(float x) {
  float e = __expf(2.f * x);
  return 1.f - 2.f / (e + 1.f);
}
static __device__ __forceinline__ float sigm(float x) {
  return 1.f / (1.f + __expf(-x));
}
static __device__ __forceinline__ void barrier_lds() {
  asm volatile("s_waitcnt lgkmcnt(0)" ::: "memory");
  __builtin_amdgcn_s_barrier();
  asm volatile("" ::: "memory");
}

// ---------------- weight prep: bf16 convert, Whh split hi/lo, bias merge ----
__global__ void k_prep(const float* __restrict__ Wih, const float* __restrict__ Whh,
                       const float* __restrict__ bih, const float* __restrict__ bhh,
                       u16* __restrict__ wih_b, u16* __restrict__ whh_hi,
                       u16* __restrict__ whh_lo, float* __restrict__ bcat) {
  size_t stride = (size_t)gridDim.x * blockDim.x;
  size_t i0 = (size_t)blockIdx.x * blockDim.x + threadIdx.x;
  const size_t n_ih = (size_t)2 * 2 * G4 * EMBD;  // [l][d][4H][E]
  for (size_t i = i0; i < n_ih; i += stride) wih_b[i] = f2bf(Wih[i]);
  const size_t n_hh = (size_t)2 * 2 * G4 * HID;   // [l][d][4H][H]
  for (size_t i = i0; i < n_hh; i += stride) {
    float w = Whh[i];
    u16 hi = f2bf(w);
    whh_hi[i] = hi;
    whh_lo[i] = f2bf(w - bf2f(hi));
  }
  for (size_t i = i0; i < 2 * 4096; i += stride) {
    size_t l = i >> 12, col = i & 4095;  // col = d*2048+g*512+u
    bcat[i] = bih[l * 4096 + col] + bhh[l * 4096 + col];
  }
}

// ---------------- embedding gather -> bf16 X [T*B, 1024] --------------------
__global__ void k_gather(const int* __restrict__ inp, const float* __restrict__ emb,
                         u16* __restrict__ X) {
  int row = blockIdx.x;  // t*32 + b
  int t = row >> 5, b = row & 31;
  int tok = inp[b * T_SEQ + t];
  const float* src = emb + (size_t)tok * EMBD + threadIdx.x * 4;
  float4 v = *reinterpret_cast<const float4*>(src);
  ushort4 o;
  o.x = f2bf(v.x); o.y = f2bf(v.y); o.z = f2bf(v.z); o.w = f2bf(v.w);
  *reinterpret_cast<ushort4*>(X + (size_t)row * EMBD + threadIdx.x * 4) = o;
}

// ---------------- xp GEMM: C[M,4096] = A[M,1024] @ B[4096,1024]^T + bias ----
// PACKED=0: A is bf16. PACKED=1: A is packed u32 (hi<<16|lo), use hi bf16.
#define GBM 128
#define GBN 128
#define GBK 64
template <int PACKED>
__global__ __launch_bounds__(256) void k_gemm(const void* __restrict__ Av,
                                              const u16* __restrict__ B,
                                              const float* __restrict__ bias,
                                              u16* __restrict__ C) {
  __shared__ u16 As[GBM][GBK];
  __shared__ u16 Bs[GBN][GBK];
  const int Kdim = 1024, Ndim = 4096;
  int bm = blockIdx.x, bn = blockIdx.y;
  int tid = threadIdx.x;
  int lane = tid & 63, wave = tid >> 6;
  int wm = wave >> 1, wn = wave & 1;
  int l15 = lane & 15, klo = (lane >> 4) * 8;
  f32x4 acc[4][4] = {};
  for (int k0 = 0; k0 < Kdim; k0 += GBK) {
#pragma unroll
    for (int s = 0; s < 4; s++) {
      int seg = tid + s * 256;
      int r = seg >> 3, cs = (seg & 7) * 8;
      if (PACKED) {
        const u32* srcp = (const u32*)Av + (size_t)(bm * GBM + r) * Kdim + k0 + cs;
        uint4 a = *reinterpret_cast<const uint4*>(srcp);
        uint4 b = *reinterpret_cast<const uint4*>(srcp + 4);
        uint4 o;
        o.x = __builtin_amdgcn_perm(a.y, a.x, 0x07060302u);
        o.y = __builtin_amdgcn_perm(a.w, a.z, 0x07060302u);
        o.z = __builtin_amdgcn_perm(b.y, b.x, 0x07060302u);
        o.w = __builtin_amdgcn_perm(b.w, b.z, 0x07060302u);
        *reinterpret_cast<uint4*>(&As[r][cs]) = o;
      } else {
        *reinterpret_cast<short8*>(&As[r][cs]) = *reinterpret_cast<const short8*>(
            (const u16*)Av + (size_t)(bm * GBM + r) * Kdim + k0 + cs);
      }
      *reinterpret_cast<short8*>(&Bs[r][cs]) =
          *reinterpret_cast<const short8*>(B + (size_t)(bn * GBN + r) * Kdim + k0 + cs);
    }
    __syncthreads();
#pragma unroll
    for (int kk = 0; kk < GBK; kk += 32) {
      short8 af[4], bfb[4];
#pragma unroll
      for (int i = 0; i < 4; i++)
        af[i] = *reinterpret_cast<const short8*>(&As[wm * 64 + i * 16 + l15][kk + klo]);
#pragma unroll
      for (int j = 0; j < 4; j++)
        bfb[j] = *reinterpret_cast<const short8*>(&Bs[wn * 64 + j * 16 + l15][kk + klo]);
#pragma unroll
      for (int i = 0; i < 4; i++)
#pragma unroll
        for (int j = 0; j < 4; j++)
          acc[i][j] = mfma16(af[i], bfb[j], acc[i][j]);
    }
    __syncthreads();
  }
  int lg4 = (lane >> 4) * 4;
#pragma unroll
  for (int i = 0; i < 4; i++) {
#pragma unroll
    for (int j = 0; j < 4; j++) {
      int n = bn * GBN + wn * 64 + j * 16 + l15;
      float bv = bias[n];
#pragma unroll
      for (int r = 0; r < 4; r++) {
        int m = bm * GBM + wm * 64 + i * 16 + lg4 + r;
        C[(size_t)m * Ndim + n] = f2bf(acc[i][j][r] + bv);
      }
    }
  }
}

// ---------------- recurrent layer: XCD-claimed workers ----------------------
// grid=2048. Each WG reads its physical XCC_ID; WGs on XCD0 claim dir-0
// slices, XCD1 claims dir-1 (device-scope atomic tickets) -> all 32
// participants of a direction PROVABLY share one L2. h published by DUAL
// store: plain (write-through -> shared local L2, updates any cached
// sentinel line) + sc0sc1 (LLC mirror). Poll sc0 (L1-bypass, local-L2 hit).
// Safety (placement-independent correctness): overflow tickets (>=1984)
// claim leftover slots from any XCD in LLC mode; consumers flip to LLC
// polls after 4096 futile rounds. Normal case: fallback never fires.
__global__ __launch_bounds__(256, 1) void k_lstm16(const u16* __restrict__ xp,
                                                   const u16* __restrict__ whh_hi,
                                                   const u16* __restrict__ whh_lo,
                                                   u32* __restrict__ ypk,
                                                   int* __restrict__ ctl) {
  __shared__ int sh[3];  // dir, slice, mode
  int tid = threadIdx.x;
  if (tid == 0) {
    u32 xcc;
    asm volatile("s_getreg_b32 %0, hwreg(HW_REG_XCC_ID)" : "=s"(xcc));
    xcc &= 7u;
    int ticket = __hip_atomic_fetch_add(ctl, 1, __ATOMIC_RELAXED,
                                        __HIP_MEMORY_SCOPE_AGENT);
    int dir = -1, slice = -1, mode = 0;
    if (ticket < TICK_OVF) {
      if (xcc <= 1u) {
        int d = (int)xcc;
        int idx = __hip_atomic_fetch_add(ctl + 1 + d, 1, __ATOMIC_RELAXED,
                                         __HIP_MEMORY_SCOPE_AGENT);
        if (idx < 32) { dir = d; slice = idx; }
      }
    } else {  // overflow: claim any leftover slot, operate in LLC mode
      for (int d = 0; d < 2 && dir < 0; d++) {
        int idx = __hip_atomic_fetch_add(ctl + 1 + d, 1, __ATOMIC_RELAXED,
                                         __HIP_MEMORY_SCOPE_AGENT);
        if (idx < 32) { dir = d; slice = idx; mode = 1; }
      }
    }
    sh[0] = dir; sh[1] = slice; sh[2] = mode;
  }
  __syncthreads();
  int dir = sh[0], slice = sh[1];
  int use_llc = sh[2];
  if (dir < 0) return;

  int wave = tid >> 6, lane = tid & 63;
  int u0 = slice * 16;
  int l15 = lane & 15, lg = lane >> 4;
  int klo = lg * 8;

  f32x4 whf[4][4], wlf[4][4];
#pragma unroll
  for (int ct = 0; ct < 4; ct++) {
    size_t wr = ((size_t)dir * G4 + ct * HID + u0 + l15) * HID + wave * 128 + klo;
#pragma unroll
    for (int kt = 0; kt < 4; kt++) {
      whf[ct][kt] = *reinterpret_cast<const f32x4*>(whh_hi + wr + kt * 32);
      wlf[ct][kt] = *reinterpret_cast<const f32x4*>(whh_lo + wr + kt * 32);
    }
  }
#pragma unroll
  for (int ct = 0; ct < 4; ct++)
#pragma unroll
    for (int kt = 0; kt < 4; kt++) {
      asm volatile("" : "+v"(whf[ct][kt]));
      asm volatile("" : "+v"(wlf[ct][kt]));
    }

  __shared__ float pgx[4][NB][16][5];  // [gate][b][uu][wave+pad]
  float cst[2] = {0.f, 0.f};
  int bj[2], uj[2];
#pragma unroll
  for (int j = 0; j < 2; j++) {
    int p = tid + 256 * j;
    uj[j] = p & 15;
    bj[j] = p >> 4;
  }

  for (int s = 0; s < T_SEQ; s++) {
    int trow = dir ? (T_SEQ - 1 - s) : s;
    short8 ah[2][4], al[2][4];
    if (s > 0) {
      int prow = dir ? (T_SEQ - s) : (s - 1);
      const u32* yb = ypk + ((size_t)prow * NB + l15) * 1024 + dir * HID + wave * 128 + klo;
      uint4 hb[2][4][2];
      int tries = 0;
      // ---- data-poll: local-L2 (sc0) fast path, LLC (sc0sc1) fallback ----
      while (true) {
        if (!use_llc) {
#pragma unroll
          for (int mt = 0; mt < 2; mt++) {
            const u32* pb = yb + (size_t)mt * 16 * 1024;
#pragma unroll
            for (int kt = 0; kt < 4; kt++) {
              asm volatile("global_load_dwordx4 %0, %1, off offset:%2 sc0"
                           : "=&v"(hb[mt][kt][0]) : "v"(pb), "i"(kt * 128));
              asm volatile("global_load_dwordx4 %0, %1, off offset:%2 sc0"
                           : "=&v"(hb[mt][kt][1]) : "v"(pb), "i"(kt * 128 + 16));
            }
          }
        } else {
#pragma unroll
          for (int mt = 0; mt < 2; mt++) {
            const u32* pb = yb + (size_t)mt * 16 * 1024;
#pragma unroll
            for (int kt = 0; kt < 4; kt++) {
              asm volatile("global_load_dwordx4 %0, %1, off offset:%2 sc0 sc1"
                           : "=&v"(hb[mt][kt][0]) : "v"(pb), "i"(kt * 128));
              asm volatile("global_load_dwordx4 %0, %1, off offset:%2 sc0 sc1"
                           : "=&v"(hb[mt][kt][1]) : "v"(pb), "i"(kt * 128 + 16));
            }
          }
        }
        asm volatile("s_waitcnt vmcnt(0)" ::: "memory");
        __builtin_amdgcn_sched_barrier(0);
        u32 mx = 0;  // SENTW == u32 max: any sentinel word makes mx == SENTW
#pragma unroll
        for (int mt = 0; mt < 2; mt++)
#pragma unroll
          for (int kt = 0; kt < 4; kt++)
#pragma unroll
            for (int h2 = 0; h2 < 2; h2++) {
              uint4 v = hb[mt][kt][h2];
              mx = max(mx, max(max(v.x, v.y), max(v.z, v.w)));
            }
        if (__all(mx != SENTW)) break;
        if (++tries == 4096) use_llc = 1;
      }
      // unpack hi|lo via byte-perms
#pragma unroll
      for (int mt = 0; mt < 2; mt++)
#pragma unroll
        for (int kt = 0; kt < 4; kt++) {
          uint4 a = hb[mt][kt][0], b = hb[mt][kt][1];
          u32 v8[8] = {a.x, a.y, a.z, a.w, b.x, b.y, b.z, b.w};
          union { short8 s8; u32 u[4]; } uh, ul;
#pragma unroll
          for (int i = 0; i < 4; i++) {
            uh.u[i] = __builtin_amdgcn_perm(v8[2 * i + 1], v8[2 * i], 0x07060302u);
            ul.u[i] = __builtin_amdgcn_perm(v8[2 * i + 1], v8[2 * i], 0x05040100u);
          }
          ah[mt][kt] = uh.s8;
          al[mt][kt] = ul.s8;
        }
    }
    // ---- issue xq loads now (no wait): latency hides under MFMA phase ----
    u32 xqr[2][4];
#pragma unroll
    for (int j = 0; j < 2; j++) {
      const u16* xb = xp + (size_t)(trow * NB + bj[j]) * XPW + dir * 2048 + u0 + uj[j];
#pragma unroll
      for (int g = 0; g < 4; g++)
        asm volatile("global_load_ushort %0, %1, off offset:%2"
                     : "=&v"(xqr[j][g]) : "v"(xb), "i"(g * HID * 2));
    }
    if (s > 0) {
      f32x4 accM[2][4], accC[2][4];
#pragma unroll
      for (int mt = 0; mt < 2; mt++)
#pragma unroll
        for (int ct = 0; ct < 4; ct++) {
          accM[mt][ct] = (f32x4){0.f, 0.f, 0.f, 0.f};
          accC[mt][ct] = (f32x4){0.f, 0.f, 0.f, 0.f};
        }
#pragma unroll
      for (int kt = 0; kt < 4; kt++)
#pragma unroll
        for (int mt = 0; mt < 2; mt++)
#pragma unroll
          for (int ct = 0; ct < 4; ct++) {
            short8 wh = __builtin_bit_cast(short8, whf[ct][kt]);
            short8 wl = __builtin_bit_cast(short8, wlf[ct][kt]);
            accM[mt][ct] = mfma16(ah[mt][kt], wh, accM[mt][ct]);
            accC[mt][ct] = mfma16(al[mt][kt], wh, accC[mt][ct]);
            accC[mt][ct] = mfma16(ah[mt][kt], wl, accC[mt][ct]);
          }
#pragma unroll
      for (int mt = 0; mt < 2; mt++)
#pragma unroll
        for (int ct = 0; ct < 4; ct++) {
          f32x4 v4 = accM[mt][ct] + accC[mt][ct];
#pragma unroll
          for (int r = 0; r < 4; r++)
            pgx[ct][mt * 16 + lg * 4 + r][l15][wave] = v4[r];
        }
    }
    barrier_lds();  // pgx writes visible
    asm volatile("s_waitcnt vmcnt(0)" ::: "memory");  // xq (+prev stores) done
    __builtin_amdgcn_sched_barrier(0);
#pragma unroll
    for (int j = 0; j < 2; j++) {
      int b = bj[j], uu = uj[j];
      float gs[4];
#pragma unroll
      for (int g = 0; g < 4; g++) {
        float v = bf2f((u16)xqr[j][g]);
        if (s > 0)
          v += (pgx[g][b][uu][0] + pgx[g][b][uu][1]) +
               (pgx[g][b][uu][2] + pgx[g][b][uu][3]);
        gs[g] = v;
      }
      float iv = sigm(gs[0]);
      float fv = sigm(gs[1]);
      float gv = fast_tanh(gs[2]);
      float ov = sigm(gs[3]);
      float c = fv * cst[j] + iv * gv;
      cst[j] = c;
      float h = ov * fast_tanh(c);
      u16 hh = f2bf(h);
      u16 hl = f2bf(h - bf2f(hh));
      size_t yo = ((size_t)trow * NB + b) * 1024 + dir * HID + u0 + uu;
      u32 pkv = ((u32)hh << 16) | hl;
      u32* addr = ypk + yo;
      // dual store: plain -> shared local L2; sc0sc1 -> LLC mirror
      asm volatile("global_store_dword %0, %1, off" :: "v"(addr), "v"(pkv) : "memory");
      asm volatile("global_store_dword %0, %1, off sc0 sc1" :: "v"(addr), "v"(pkv) : "memory");
    }
    barrier_lds();  // protect pgx reads before next step's writes
  }
}

// ---------------- final pooled dot ------------------------------------------
__global__ void k_out(const u32* __restrict__ ypk, const float* __restrict__ wout,
                      const float* __restrict__ bout, float* __restrict__ out) {
  int b = blockIdx.x;
  __shared__ float red[256];
  float s = 0.f;
  for (int c = threadIdx.x; c < 1024; c += 256) {
    size_t row = (c < 512) ? ((size_t)(T_SEQ - 1) * NB + b) : (size_t)b;
    u32 pk = ypk[row * 1024 + c];
    float h = bf2f((u16)(pk >> 16)) + bf2f((u16)(pk & 0xFFFFu));
    s += h * wout[c];
  }
  red[threadIdx.x] = s;
  __syncthreads();
  for (int st = 128; st > 0; st >>= 1) {
    if (threadIdx.x < st) red[threadIdx.x] += red[threadIdx.x + st];
    __syncthreads();
  }
  if (threadIdx.x == 0) out[b] = red[0] + bout[0];
}

extern "C" void kernel_launch(void* const* d_in, const int* in_sizes, int n_in,
                              void* d_out, int out_size, void* d_ws, size_t ws_size,
                              hipStream_t stream) {
  const int*   inp  = (const int*)d_in[0];
  const float* emb  = (const float*)d_in[1];
  const float* Wih  = (const float*)d_in[2];
  const float* Whh  = (const float*)d_in[3];
  const float* bih  = (const float*)d_in[4];
  const float* bhh  = (const float*)d_in[5];
  const float* Wout = (const float*)d_in[6];
  const float* bout = (const float*)d_in[7];
  float* out = (float*)d_out;
  char* ws = (char*)d_ws;

  const size_t SZ_XP  = (size_t)NROWS * XPW * 2;   // 134 MB
  const size_t SZ_YPK = (size_t)NROWS * 1024 * 4;  // 67 MB
  const size_t SZ_WIH = (size_t)2 * 4096 * 1024 * 2;
  const size_t SZ_WHH = (size_t)2 * 2 * G4 * HID * 2;
  size_t off = 0;
  auto alloc = [&](size_t n) { size_t o = off; off += (n + 255) & ~(size_t)255; return o; };
  size_t o_xp   = alloc(SZ_XP);
  size_t o_ypkA = alloc(SZ_YPK);
  size_t o_ypkB = alloc(SZ_YPK);  // first 34 MB doubles as X1 (dead pre-memset)
  size_t o_wih  = alloc(SZ_WIH);
  size_t o_whhh = alloc(SZ_WHH);
  size_t o_whhl = alloc(SZ_WHH);
  size_t o_bc   = alloc(2 * 4096 * sizeof(float));
  size_t o_ctl  = alloc(2 * 3 * sizeof(int));
  if (ws_size < off) return;

  u16* xp   = (u16*)(ws + o_xp);
  u32* ypkA = (u32*)(ws + o_ypkA);
  u32* ypkB = (u32*)(ws + o_ypkB);
  u16* x1   = (u16*)(ws + o_ypkB);  // alias: dead before ypkB memset
  u16* wihb = (u16*)(ws + o_wih);
  u16* whhh = (u16*)(ws + o_whhh);
  u16* whhl = (u16*)(ws + o_whhl);
  float* bc = (float*)(ws + o_bc);
  int* ctl  = (int*)(ws + o_ctl);

  (void)hipMemsetAsync(ctl, 0, 2 * 3 * sizeof(int), stream);
  (void)hipMemsetAsync(ypkA, 0xFF, SZ_YPK, stream);  // sentinel layer-1 h
  k_prep<<<4096, 256, 0, stream>>>(Wih, Whh, bih, bhh, wihb, whhh, whhl, bc);
  k_gather<<<NROWS, 256, 0, stream>>>(inp, emb, x1);
  k_gemm<0><<<dim3(NROWS / GBM, XPW / GBN), 256, 0, stream>>>(x1, wihb, bc, xp);
  k_lstm16<<<NGRID, 256, 0, stream>>>(xp, whhh, whhl, ypkA, ctl);
  k_gemm<1><<<dim3(NROWS / GBM, XPW / GBN), 256, 0, stream>>>(
      ypkA, wihb + (size_t)4096 * 1024, bc + 4096, xp);
  (void)hipMemsetAsync(ypkB, 0xFF, SZ_YPK, stream);  // sentinel layer-2 h
  k_lstm16<<<NGRID, 256, 0, stream>>>(xp, whhh + (size_t)2 * G4 * HID,
                                      whhl + (size_t)2 * G4 * HID, ypkB, ctl + 3);
  k_out<<<NB, 256, 0, stream>>>(ypkB, Wout, bout, out);
}